// Round 9
// baseline (383.078 us; speedup 1.0000x reference)
//
#include <hip/hip_runtime.h>
#include <hip/hip_bf16.h>

// Problem shape (fixed by setup_inputs)
#define B_DIM 512
#define L_DIM 16384
#define TPB   512                 // threads per block, kernel 1
#define KSTEPS 32                 // timesteps per thread
#define NGROUP 8                  // 8 groups of 4 steps (20-reg staging buffer)
#define CONT_W  0.05f

#define LOG2E 1.4426950408889634f
#define LN2F  0.6931471805599453f

#if __has_builtin(__builtin_amdgcn_exp2f)
#define EXP2F(x) __builtin_amdgcn_exp2f(x)
#else
#define EXP2F(x) exp2f(x)
#endif
#if __has_builtin(__builtin_amdgcn_logf)
#define LOG2F(x) __builtin_amdgcn_logf(x)   // v_log_f32 is log2
#else
#define LOG2F(x) log2f(x)
#endif
#if __has_builtin(__builtin_amdgcn_rcpf)
#define RCPF(x) __builtin_amdgcn_rcpf(x)
#else
#define RCPF(x) (1.0f / (x))
#endif

__device__ __forceinline__ float sel3(int k, float a, float b, float c) {
    return (k == 0) ? a : ((k == 1) ? b : c);
}

// -------- Kernel 1: one block per sequence --------
// Per sequence b, 16 floats in ws:
//  [0..8] P (LINEAR domain, row-major, scaled)  [9] s (log2 scale)
//  [10] score partial (log2 domain, t>=1)  [11] focal sum  [12] n_valid
//  [13] n_trans candidates  [14] transition count  [15] mask count
__global__ __launch_bounds__(TPB, 8) void pass1(   // 8 waves/EU -> VGPR<=64
    const float* __restrict__ logits,
    const int* __restrict__ targets,
    const int* __restrict__ mask,            // jnp.bool_ arrives as int32
    const float* __restrict__ trans,
    float* __restrict__ partials)
{
    const int b   = blockIdx.x;
    const int tid = threadIdx.x;
    const size_t base = (size_t)b * L_DIM;

    // transitions in log2 domain + linear forms W = 2^T (uniform -> SGPRs)
    const float t00 = trans[0]*LOG2E, t01 = trans[1]*LOG2E, t02 = trans[2]*LOG2E;
    const float t10 = trans[3]*LOG2E, t11 = trans[4]*LOG2E, t12 = trans[5]*LOG2E;
    const float t20 = trans[6]*LOG2E, t21 = trans[7]*LOG2E, t22 = trans[8]*LOG2E;
    const float w00 = EXP2F(t00), w01 = EXP2F(t01), w02 = EXP2F(t02);
    const float w10 = EXP2F(t10), w11 = EXP2F(t11), w12 = EXP2F(t12);
    const float w20 = EXP2F(t20), w21 = EXP2F(t21), w22 = EXP2F(t22);

    const int t0 = tid * KSTEPS;

    // P = identity (linear), scale s_acc (log2)
    float p00 = 1.f, p01 = 0.f, p02 = 0.f;
    float p10 = 0.f, p11 = 1.f, p12 = 0.f;
    float p20 = 0.f, p21 = 0.f, p22 = 1.f;
    float s_acc = 0.f;

    // boundary state from t0-1
    int pred_prev = 0, tag_prev = 0;
    if (t0 > 0) {
        const float* r = logits + (base + t0 - 1) * 3;
        float a = r[0], bb = r[1], c = r[2];
        pred_prev = (bb > a) ? ((c > bb) ? 2 : 1) : ((c > a) ? 2 : 0);
        int tp = targets[base + t0 - 1];
        tag_prev = (tp < 0) ? 0 : ((tp > 2) ? 2 : tp);
    }

    float score2 = 0.f, focalP = 0.f, nvalidP = 0.f;
    float ntransP = 0.f, tcountP = 0.f, mcountP = 0.f;

    auto doStep = [&](int t, float e0, float e1, float e2, int tgt, int mkv) {
        const bool mb = (mkv != 0);
        mcountP += mb ? 1.f : 0.f;
        const bool valid = mb && (tgt >= 0) && (tgt < 3);
        const int  tag   = (tgt < 0) ? 0 : ((tgt > 2) ? 2 : tgt);
        const float f0 = e0 * LOG2E, f1 = e1 * LOG2E, f2 = e2 * LOG2E;
        const float E0 = EXP2F(f0), E1 = EXP2F(f1), E2 = EXP2F(f2);
        const float S  = E0 + E1 + E2;
        const float ftag = sel3(tag, f0, f1, f2);
        const float ce2 = LOG2F(S) - ftag;
        const float pt  = sel3(tag, E0, E1, E2) * RCPF(S);
        const float om  = 1.f - pt;
        if (valid) { focalP += om * om * (ce2 * LN2F); nvalidP += 1.f; }
        const int pred = (e1 > e0) ? ((e2 > e1) ? 2 : 1) : ((e2 > e0) ? 2 : 0);
        if (t >= 1) {
            if (valid) { ntransP += 1.f; tcountP += (pred != pred_prev) ? 1.f : 0.f; }
            if (mb) {
                const float c0 = sel3(tag, t00, t01, t02);
                const float c1 = sel3(tag, t10, t11, t12);
                const float c2 = sel3(tag, t20, t21, t22);
                score2 += sel3(tag_prev, c0, c1, c2) + ftag;
                // P <- (P*W) .* colE   (27 FMA + 9 mul)
                const float m0 = p00*w00 + p01*w10 + p02*w20;
                const float m1 = p00*w01 + p01*w11 + p02*w21;
                const float m2 = p00*w02 + p01*w12 + p02*w22;
                const float m3 = p10*w00 + p11*w10 + p12*w20;
                const float m4 = p10*w01 + p11*w11 + p12*w21;
                const float m5 = p10*w02 + p11*w12 + p12*w22;
                const float m6 = p20*w00 + p21*w10 + p22*w20;
                const float m7 = p20*w01 + p21*w11 + p22*w21;
                const float m8 = p20*w02 + p21*w12 + p22*w22;
                p00 = m0*E0; p01 = m1*E1; p02 = m2*E2;
                p10 = m3*E0; p11 = m4*E1; p12 = m5*E2;
                p20 = m6*E0; p21 = m7*E1; p22 = m8*E2;
            }
        }
        pred_prev = pred; tag_prev = tag;
    };

    const float4* Lp = reinterpret_cast<const float4*>(logits + (base + (size_t)t0) * 3);
    const int4*   Tp = reinterpret_cast<const int4*>(targets + base + t0);
    const int4*   Mp = reinterpret_cast<const int4*>(mask    + base + t0);

    #pragma unroll 1
    for (int g = 0; g < NGROUP; ++g) {
        float la[12]; int ta[4]; int ma[4];     // 20-reg staging buffer
        #pragma unroll
        for (int j = 0; j < 3; ++j)
            *reinterpret_cast<float4*>(&la[4 * j]) = Lp[g * 3 + j];
        *reinterpret_cast<int4*>(&ta[0]) = Tp[g];
        *reinterpret_cast<int4*>(&ma[0]) = Mp[g];

        const int tg = t0 + g * 4;
        #pragma unroll
        for (int u = 0; u < 4; ++u)
            doStep(tg + u, la[u * 3 + 0], la[u * 3 + 1], la[u * 3 + 2], ta[u], ma[u]);

        // rescale by exponent of max entry (bit ops only)
        float mx = fmaxf(fmaxf(fmaxf(fmaxf(p00, p01), fmaxf(p02, p10)),
                               fmaxf(fmaxf(p11, p12), fmaxf(p20, p21))), p22);
        const unsigned bbits = __float_as_uint(mx);
        const int ex = (int)((bbits >> 23) & 255u) - 127;
        const float sc = __uint_as_float((unsigned)(127 - ex) << 23);  // 2^-ex
        p00 *= sc; p01 *= sc; p02 *= sc;
        p10 *= sc; p11 *= sc; p12 *= sc;
        p20 *= sc; p21 *= sc; p22 *= sc;
        s_acc += (float)ex;
    }

    // ---- block tree-reduction (linear matrices + scales; scalar sums) ----
    __shared__ float sP[TPB][10];
    __shared__ float sS[TPB][6];
    sP[tid][0] = p00; sP[tid][1] = p01; sP[tid][2] = p02;
    sP[tid][3] = p10; sP[tid][4] = p11; sP[tid][5] = p12;
    sP[tid][6] = p20; sP[tid][7] = p21; sP[tid][8] = p22;
    sP[tid][9] = s_acc;
    sS[tid][0] = score2; sS[tid][1] = focalP; sS[tid][2] = nvalidP;
    sS[tid][3] = ntransP; sS[tid][4] = tcountP; sS[tid][5] = mcountP;
    __syncthreads();

    for (int off = 1; off < TPB; off <<= 1) {
        if ((tid & (2 * off - 1)) == 0) {
            float A[9], Bm[9], Cn[9];
            #pragma unroll
            for (int k = 0; k < 9; ++k) { A[k] = sP[tid][k]; Bm[k] = sP[tid + off][k]; }
            float s = sP[tid][9] + sP[tid + off][9];
            #pragma unroll
            for (int i = 0; i < 3; ++i)
                #pragma unroll
                for (int j = 0; j < 3; ++j)
                    Cn[i * 3 + j] = A[i * 3 + 0] * Bm[0 * 3 + j]
                                  + A[i * 3 + 1] * Bm[1 * 3 + j]
                                  + A[i * 3 + 2] * Bm[2 * 3 + j];
            float mx = Cn[0];
            #pragma unroll
            for (int k = 1; k < 9; ++k) mx = fmaxf(mx, Cn[k]);
            const unsigned bbits = __float_as_uint(mx);
            const int ex = (int)((bbits >> 23) & 255u) - 127;
            const float sc = __uint_as_float((unsigned)(127 - ex) << 23);
            #pragma unroll
            for (int k = 0; k < 9; ++k) sP[tid][k] = Cn[k] * sc;
            sP[tid][9] = s + (float)ex;
            #pragma unroll
            for (int k = 0; k < 6; ++k) sS[tid][k] += sS[tid + off][k];
        }
        __syncthreads();
    }

    if (tid == 0) {
        float* o = partials + (size_t)b * 16;
        #pragma unroll
        for (int k = 0; k < 10; ++k) o[k] = sP[0][k];
        #pragma unroll
        for (int k = 0; k < 6; ++k) o[10 + k] = sS[0][k];
    }
}

// -------- Kernel 2: finalize, one thread per sequence, single block --------
__global__ __launch_bounds__(B_DIM) void pass2(
    const float* __restrict__ logits,
    const int* __restrict__ targets,
    const float* __restrict__ start_trans,
    const float* __restrict__ end_trans,
    const float* __restrict__ partials,
    float* __restrict__ out)
{
    const int tid = threadIdx.x;
    double v_llh, v_focal, v_nv, v_nt, v_tc;

    {
        const int b = tid;
        const float* pp = partials + (size_t)b * 16;
        float P[9];
        #pragma unroll
        for (int k = 0; k < 9; ++k) P[k] = pp[k];
        const float s_scale = pp[9];
        const float score2  = pp[10];
        v_focal = (double)pp[11];
        v_nv    = (double)pp[12];
        v_nt    = (double)pp[13];
        v_tc    = (double)pp[14];
        const float mcount = pp[15];

        const size_t base = (size_t)b * L_DIM;
        const float e0 = logits[base * 3 + 0];
        const float e1 = logits[base * 3 + 1];
        const float e2 = logits[base * 3 + 2];
        const int tg0  = targets[base];
        const int tag0 = (tg0 < 0) ? 0 : ((tg0 > 2) ? 2 : tg0);

        const float a0 = (start_trans[0] + e0) * LOG2E;
        const float a1 = (start_trans[1] + e1) * LOG2E;
        const float a2 = (start_trans[2] + e2) * LOG2E;
        const float am = fmaxf(fmaxf(a0, a1), a2);
        const float al0 = EXP2F(a0 - am), al1 = EXP2F(a1 - am), al2 = EXP2F(a2 - am);
        const float af0 = al0 * P[0] + al1 * P[3] + al2 * P[6];
        const float af1 = al0 * P[1] + al1 * P[4] + al2 * P[7];
        const float af2 = al0 * P[2] + al1 * P[5] + al2 * P[8];
        const float et0 = EXP2F(end_trans[0] * LOG2E);
        const float et1 = EXP2F(end_trans[1] * LOG2E);
        const float et2 = EXP2F(end_trans[2] * LOG2E);
        const float d   = af0 * et0 + af1 * et1 + af2 * et2;
        const float den = (LOG2F(d) + am + s_scale) * LN2F;

        int seq_end = (int)(mcount + 0.5f) - 1;
        if (seq_end < 0) seq_end = 0;
        const int ltg = targets[base + seq_end];
        const int last_tag = (ltg < 0) ? 0 : ((ltg > 2) ? 2 : ltg);

        const float sc0 = start_trans[tag0] + sel3(tag0, e0, e1, e2);
        const float numer = sc0 + score2 * LN2F + end_trans[last_tag];
        v_llh = (double)numer - (double)den;
    }

    __shared__ double sred[B_DIM];
    double tot[5];
    double vals[5] = { v_llh, v_focal, v_nv, v_nt, v_tc };
    for (int q = 0; q < 5; ++q) {
        sred[tid] = vals[q];
        __syncthreads();
        for (int off = B_DIM / 2; off > 0; off >>= 1) {
            if (tid < off) sred[tid] += sred[tid + off];
            __syncthreads();
        }
        if (tid == 0) tot[q] = sred[0];
        __syncthreads();
    }

    if (tid == 0) {
        double nvv = (tot[2] > 1.0) ? tot[2] : 1.0;
        double ntt = (tot[3] > 1.0) ? tot[3] : 1.0;
        double focal_mean = tot[1] / nvv;
        double crf = -(tot[0] / (double)B_DIM);
        double cont = tot[4] / ntt;
        out[0] = (float)(focal_mean + crf + (double)CONT_W * cont);
    }
}

extern "C" void kernel_launch(void* const* d_in, const int* in_sizes, int n_in,
                              void* d_out, int out_size, void* d_ws, size_t ws_size,
                              hipStream_t stream) {
    const float* logits       = (const float*)d_in[0];
    const int*   targets      = (const int*)d_in[1];
    const int*   mask         = (const int*)d_in[2];   // bool stored as int32
    const float* start_trans  = (const float*)d_in[3];
    const float* end_trans    = (const float*)d_in[4];
    const float* trans        = (const float*)d_in[5];
    float* out = (float*)d_out;
    float* partials = (float*)d_ws;   // 512 * 16 floats = 32 KB

    pass1<<<B_DIM, TPB, 0, stream>>>(logits, targets, mask, trans, partials);
    pass2<<<1, B_DIM, 0, stream>>>(logits, targets, start_trans, end_trans, partials, out);
}

// Round 10
// 270.173 us; speedup vs baseline: 1.4179x; 1.4179x over previous
//
#include <hip/hip_runtime.h>
#include <hip/hip_bf16.h>

// Problem shape (fixed by setup_inputs)
#define B_DIM 512
#define L_DIM 16384
#define TPB   512                 // threads per block, kernel 1
#define KSTEPS 32                 // timesteps per thread
#define NGROUP 8                  // 8 groups of 4 steps, double-buffered A/B
#define CONT_W  0.05f

#define LOG2E 1.4426950408889634f
#define LN2F  0.6931471805599453f

#if __has_builtin(__builtin_amdgcn_exp2f)
#define EXP2F(x) __builtin_amdgcn_exp2f(x)
#else
#define EXP2F(x) exp2f(x)
#endif
#if __has_builtin(__builtin_amdgcn_logf)
#define LOG2F(x) __builtin_amdgcn_logf(x)   // v_log_f32 is log2
#else
#define LOG2F(x) log2f(x)
#endif
#if __has_builtin(__builtin_amdgcn_rcpf)
#define RCPF(x) __builtin_amdgcn_rcpf(x)
#else
#define RCPF(x) (1.0f / (x))
#endif

__device__ __forceinline__ float sel3(int k, float a, float b, float c) {
    return (k == 0) ? a : ((k == 1) ? b : c);
}

// -------- Kernel 1: one block per sequence --------
// Per sequence b, 16 floats in ws:
//  [0..8] P (LINEAR domain, row-major, scaled)  [9] s (log2 scale)
//  [10] score partial (log2 domain, t>=1)  [11] focal sum  [12] n_valid
//  [13] n_trans candidates  [14] transition count  [15] mask count
__global__ __launch_bounds__(TPB) void pass1(     // natural VGPR allocation!
    const float* __restrict__ logits,
    const int* __restrict__ targets,
    const int* __restrict__ mask,            // jnp.bool_ arrives as int32
    const float* __restrict__ trans,
    float* __restrict__ partials)
{
    const int b   = blockIdx.x;
    const int tid = threadIdx.x;
    const size_t base = (size_t)b * L_DIM;

    // transitions in log2 domain + linear forms W = 2^T (uniform -> SGPRs)
    const float t00 = trans[0]*LOG2E, t01 = trans[1]*LOG2E, t02 = trans[2]*LOG2E;
    const float t10 = trans[3]*LOG2E, t11 = trans[4]*LOG2E, t12 = trans[5]*LOG2E;
    const float t20 = trans[6]*LOG2E, t21 = trans[7]*LOG2E, t22 = trans[8]*LOG2E;
    const float w00 = EXP2F(t00), w01 = EXP2F(t01), w02 = EXP2F(t02);
    const float w10 = EXP2F(t10), w11 = EXP2F(t11), w12 = EXP2F(t12);
    const float w20 = EXP2F(t20), w21 = EXP2F(t21), w22 = EXP2F(t22);

    const int t0 = tid * KSTEPS;

    // P = identity (linear), scale s_acc (log2)
    float p00 = 1.f, p01 = 0.f, p02 = 0.f;
    float p10 = 0.f, p11 = 1.f, p12 = 0.f;
    float p20 = 0.f, p21 = 0.f, p22 = 1.f;
    float s_acc = 0.f;

    // boundary state from t0-1
    int pred_prev = 0, tag_prev = 0;
    if (t0 > 0) {
        const float* r = logits + (base + t0 - 1) * 3;
        float a = r[0], bb = r[1], c = r[2];
        pred_prev = (bb > a) ? ((c > bb) ? 2 : 1) : ((c > a) ? 2 : 0);
        int tp = targets[base + t0 - 1];
        tag_prev = (tp < 0) ? 0 : ((tp > 2) ? 2 : tp);
    }

    float score2 = 0.f, focalP = 0.f, nvalidP = 0.f;
    float ntransP = 0.f, tcountP = 0.f, mcountP = 0.f;

    auto doStep = [&](int t, float e0, float e1, float e2, int tgt, int mkv) {
        const bool mb = (mkv != 0);
        mcountP += mb ? 1.f : 0.f;
        const bool valid = mb && (tgt >= 0) && (tgt < 3);
        const int  tag   = (tgt < 0) ? 0 : ((tgt > 2) ? 2 : tgt);
        const float f0 = e0 * LOG2E, f1 = e1 * LOG2E, f2 = e2 * LOG2E;
        const float E0 = EXP2F(f0), E1 = EXP2F(f1), E2 = EXP2F(f2);
        const float S  = E0 + E1 + E2;
        const float ftag = sel3(tag, f0, f1, f2);
        const float ce2 = LOG2F(S) - ftag;
        const float pt  = sel3(tag, E0, E1, E2) * RCPF(S);
        const float om  = 1.f - pt;
        if (valid) { focalP += om * om * (ce2 * LN2F); nvalidP += 1.f; }
        const int pred = (e1 > e0) ? ((e2 > e1) ? 2 : 1) : ((e2 > e0) ? 2 : 0);
        if (t >= 1) {
            if (valid) { ntransP += 1.f; tcountP += (pred != pred_prev) ? 1.f : 0.f; }
            if (mb) {
                const float c0 = sel3(tag, t00, t01, t02);
                const float c1 = sel3(tag, t10, t11, t12);
                const float c2 = sel3(tag, t20, t21, t22);
                score2 += sel3(tag_prev, c0, c1, c2) + ftag;
                // P <- (P*W) .* colE   (27 FMA + 9 mul)
                const float m0 = p00*w00 + p01*w10 + p02*w20;
                const float m1 = p00*w01 + p01*w11 + p02*w21;
                const float m2 = p00*w02 + p01*w12 + p02*w22;
                const float m3 = p10*w00 + p11*w10 + p12*w20;
                const float m4 = p10*w01 + p11*w11 + p12*w21;
                const float m5 = p10*w02 + p11*w12 + p12*w22;
                const float m6 = p20*w00 + p21*w10 + p22*w20;
                const float m7 = p20*w01 + p21*w11 + p22*w21;
                const float m8 = p20*w02 + p21*w12 + p22*w22;
                p00 = m0*E0; p01 = m1*E1; p02 = m2*E2;
                p10 = m3*E0; p11 = m4*E1; p12 = m5*E2;
                p20 = m6*E0; p21 = m7*E1; p22 = m8*E2;
            }
        }
        pred_prev = pred; tag_prev = tag;
    };

    const float4* Lp = reinterpret_cast<const float4*>(logits + (base + (size_t)t0) * 3);
    const int4*   Tp = reinterpret_cast<const int4*>(targets + base + t0);
    const int4*   Mp = reinterpret_cast<const int4*>(mask    + base + t0);

    auto loadGroup = [&](int g, float (&la)[12], int (&ta)[4], int (&ma)[4]) {
        #pragma unroll
        for (int j = 0; j < 3; ++j)
            *reinterpret_cast<float4*>(&la[4 * j]) = Lp[g * 3 + j];
        *reinterpret_cast<int4*>(&ta[0]) = Tp[g];
        *reinterpret_cast<int4*>(&ma[0]) = Mp[g];
    };

    auto computeGroup = [&](int g, const float (&la)[12], const int (&ta)[4], const int (&ma)[4]) {
        const int tg = t0 + g * 4;
        #pragma unroll
        for (int u = 0; u < 4; ++u)
            doStep(tg + u, la[u * 3 + 0], la[u * 3 + 1], la[u * 3 + 2], ta[u], ma[u]);
        // rescale by exponent of max entry (bit ops only)
        float mx = fmaxf(fmaxf(fmaxf(fmaxf(p00, p01), fmaxf(p02, p10)),
                               fmaxf(fmaxf(p11, p12), fmaxf(p20, p21))), p22);
        const unsigned bbits = __float_as_uint(mx);
        const int ex = (int)((bbits >> 23) & 255u) - 127;
        const float sc = __uint_as_float((unsigned)(127 - ex) << 23);  // 2^-ex
        p00 *= sc; p01 *= sc; p02 *= sc;
        p10 *= sc; p11 *= sc; p12 *= sc;
        p20 *= sc; p21 *= sc; p22 *= sc;
        s_acc += (float)ex;
    };

    // software pipeline: load g+1 before computing g (register double-buffer)
    float laA[12], laB[12];
    int taA[4], taB[4], maA[4], maB[4];
    loadGroup(0, laA, taA, maA);

    #pragma unroll 1
    for (int gg = 0; gg < NGROUP; gg += 2) {
        loadGroup(gg + 1, laB, taB, maB);          // prefetch B under compute A
        computeGroup(gg, laA, taA, maA);
        if (gg + 2 < NGROUP)
            loadGroup(gg + 2, laA, taA, maA);      // prefetch A under compute B
        computeGroup(gg + 1, laB, taB, maB);
    }

    // ---- block tree-reduction (linear matrices + scales; scalar sums) ----
    __shared__ float sP[TPB][10];
    __shared__ float sS[TPB][6];
    sP[tid][0] = p00; sP[tid][1] = p01; sP[tid][2] = p02;
    sP[tid][3] = p10; sP[tid][4] = p11; sP[tid][5] = p12;
    sP[tid][6] = p20; sP[tid][7] = p21; sP[tid][8] = p22;
    sP[tid][9] = s_acc;
    sS[tid][0] = score2; sS[tid][1] = focalP; sS[tid][2] = nvalidP;
    sS[tid][3] = ntransP; sS[tid][4] = tcountP; sS[tid][5] = mcountP;
    __syncthreads();

    for (int off = 1; off < TPB; off <<= 1) {
        if ((tid & (2 * off - 1)) == 0) {
            float A[9], Bm[9], Cn[9];
            #pragma unroll
            for (int k = 0; k < 9; ++k) { A[k] = sP[tid][k]; Bm[k] = sP[tid + off][k]; }
            float s = sP[tid][9] + sP[tid + off][9];
            #pragma unroll
            for (int i = 0; i < 3; ++i)
                #pragma unroll
                for (int j = 0; j < 3; ++j)
                    Cn[i * 3 + j] = A[i * 3 + 0] * Bm[0 * 3 + j]
                                  + A[i * 3 + 1] * Bm[1 * 3 + j]
                                  + A[i * 3 + 2] * Bm[2 * 3 + j];
            float mx = Cn[0];
            #pragma unroll
            for (int k = 1; k < 9; ++k) mx = fmaxf(mx, Cn[k]);
            const unsigned bbits = __float_as_uint(mx);
            const int ex = (int)((bbits >> 23) & 255u) - 127;
            const float sc = __uint_as_float((unsigned)(127 - ex) << 23);
            #pragma unroll
            for (int k = 0; k < 9; ++k) sP[tid][k] = Cn[k] * sc;
            sP[tid][9] = s + (float)ex;
            #pragma unroll
            for (int k = 0; k < 6; ++k) sS[tid][k] += sS[tid + off][k];
        }
        __syncthreads();
    }

    if (tid == 0) {
        float* o = partials + (size_t)b * 16;
        #pragma unroll
        for (int k = 0; k < 10; ++k) o[k] = sP[0][k];
        #pragma unroll
        for (int k = 0; k < 6; ++k) o[10 + k] = sS[0][k];
    }
}

// -------- Kernel 2: finalize, one thread per sequence, single block --------
__global__ __launch_bounds__(B_DIM) void pass2(
    const float* __restrict__ logits,
    const int* __restrict__ targets,
    const float* __restrict__ start_trans,
    const float* __restrict__ end_trans,
    const float* __restrict__ partials,
    float* __restrict__ out)
{
    const int tid = threadIdx.x;
    double v_llh, v_focal, v_nv, v_nt, v_tc;

    {
        const int b = tid;
        const float* pp = partials + (size_t)b * 16;
        float P[9];
        #pragma unroll
        for (int k = 0; k < 9; ++k) P[k] = pp[k];
        const float s_scale = pp[9];
        const float score2  = pp[10];
        v_focal = (double)pp[11];
        v_nv    = (double)pp[12];
        v_nt    = (double)pp[13];
        v_tc    = (double)pp[14];
        const float mcount = pp[15];

        const size_t base = (size_t)b * L_DIM;
        const float e0 = logits[base * 3 + 0];
        const float e1 = logits[base * 3 + 1];
        const float e2 = logits[base * 3 + 2];
        const int tg0  = targets[base];
        const int tag0 = (tg0 < 0) ? 0 : ((tg0 > 2) ? 2 : tg0);

        const float a0 = (start_trans[0] + e0) * LOG2E;
        const float a1 = (start_trans[1] + e1) * LOG2E;
        const float a2 = (start_trans[2] + e2) * LOG2E;
        const float am = fmaxf(fmaxf(a0, a1), a2);
        const float al0 = EXP2F(a0 - am), al1 = EXP2F(a1 - am), al2 = EXP2F(a2 - am);
        const float af0 = al0 * P[0] + al1 * P[3] + al2 * P[6];
        const float af1 = al0 * P[1] + al1 * P[4] + al2 * P[7];
        const float af2 = al0 * P[2] + al1 * P[5] + al2 * P[8];
        const float et0 = EXP2F(end_trans[0] * LOG2E);
        const float et1 = EXP2F(end_trans[1] * LOG2E);
        const float et2 = EXP2F(end_trans[2] * LOG2E);
        const float d   = af0 * et0 + af1 * et1 + af2 * et2;
        const float den = (LOG2F(d) + am + s_scale) * LN2F;

        int seq_end = (int)(mcount + 0.5f) - 1;
        if (seq_end < 0) seq_end = 0;
        const int ltg = targets[base + seq_end];
        const int last_tag = (ltg < 0) ? 0 : ((ltg > 2) ? 2 : ltg);

        const float sc0 = start_trans[tag0] + sel3(tag0, e0, e1, e2);
        const float numer = sc0 + score2 * LN2F + end_trans[last_tag];
        v_llh = (double)numer - (double)den;
    }

    __shared__ double sred[B_DIM];
    double tot[5];
    double vals[5] = { v_llh, v_focal, v_nv, v_nt, v_tc };
    for (int q = 0; q < 5; ++q) {
        sred[tid] = vals[q];
        __syncthreads();
        for (int off = B_DIM / 2; off > 0; off >>= 1) {
            if (tid < off) sred[tid] += sred[tid + off];
            __syncthreads();
        }
        if (tid == 0) tot[q] = sred[0];
        __syncthreads();
    }

    if (tid == 0) {
        double nvv = (tot[2] > 1.0) ? tot[2] : 1.0;
        double ntt = (tot[3] > 1.0) ? tot[3] : 1.0;
        double focal_mean = tot[1] / nvv;
        double crf = -(tot[0] / (double)B_DIM);
        double cont = tot[4] / ntt;
        out[0] = (float)(focal_mean + crf + (double)CONT_W * cont);
    }
}

extern "C" void kernel_launch(void* const* d_in, const int* in_sizes, int n_in,
                              void* d_out, int out_size, void* d_ws, size_t ws_size,
                              hipStream_t stream) {
    const float* logits       = (const float*)d_in[0];
    const int*   targets      = (const int*)d_in[1];
    const int*   mask         = (const int*)d_in[2];   // bool stored as int32
    const float* start_trans  = (const float*)d_in[3];
    const float* end_trans    = (const float*)d_in[4];
    const float* trans        = (const float*)d_in[5];
    float* out = (float*)d_out;
    float* partials = (float*)d_ws;   // 512 * 16 floats = 32 KB

    pass1<<<B_DIM, TPB, 0, stream>>>(logits, targets, mask, trans, partials);
    pass2<<<1, B_DIM, 0, stream>>>(logits, targets, start_trans, end_trans, partials, out);
}